// Round 12
// baseline (177.841 us; speedup 1.0000x reference)
//
#include <hip/hip_runtime.h>
#include <hip/hip_bf16.h>
#include <math.h>

// Problem constants (from reference setup_inputs)
constexpr int B_  = 8;
constexpr int CIN = 3;
constexpr int C_  = 64;
constexpr int H_  = 256;
constexpr int W_  = 256;
constexpr int TAPS = 9;   // K*K, K=3

typedef float f32x4 __attribute__((ext_vector_type(4)));

// ============================================================================
// Kernel 1 (compute-bound, ~VALU roofline): kern = conv1x1(relu(conv3x3(lr)))
// ============================================================================
__global__ __launch_bounds__(256, 4)
void hsa_kern(const float* __restrict__ lr,
              const float* __restrict__ w1,
              const float* __restrict__ b1,
              const float* __restrict__ w2,
              const float* __restrict__ b2,
              float* __restrict__ kws)
{
    __shared__ float w2t[C_][12];       // transposed 1x1 weights

    const int tid = threadIdx.x;
    const int blk = blockIdx.x;         // 0 .. B_*H_-1
    const int b = blk / H_;
    const int y = blk % H_;

    for (int i = tid; i < TAPS * C_; i += 256) {
        const int t = i / C_;
        const int c = i % C_;
        w2t[c][t] = w2[i];
    }
    __syncthreads();

    const int x = tid;                  // 0..255
    float win[CIN][3][3];
    #pragma unroll
    for (int ci = 0; ci < CIN; ++ci) {
        #pragma unroll
        for (int r = 0; r < 3; ++r) {
            const int yy = y + r - 1;
            const bool vy = (unsigned)yy < (unsigned)H_;
            const float* row = lr + ((size_t)(b * CIN + ci) * H_ + yy) * W_;
            win[ci][r][0] = (vy && x > 0)       ? row[x - 1] : 0.f;
            win[ci][r][1] = vy                   ? row[x]     : 0.f;
            win[ci][r][2] = (vy && x < W_ - 1)  ? row[x + 1] : 0.f;
        }
    }

    float acc[TAPS];
    #pragma unroll
    for (int t = 0; t < TAPS; ++t) acc[t] = b2[t];

    for (int c = 0; c < C_; ++c) {
        const float* wc = w1 + c * 27;
        float h0 = b1[c], h1 = 0.f, h2 = 0.f;
        #pragma unroll
        for (int r = 0; r < 3; ++r)
            #pragma unroll
            for (int j = 0; j < 3; ++j) {
                h0 = fmaf(wc[(0 * 3 + r) * 3 + j], win[0][r][j], h0);
                h1 = fmaf(wc[(1 * 3 + r) * 3 + j], win[1][r][j], h1);
                h2 = fmaf(wc[(2 * 3 + r) * 3 + j], win[2][r][j], h2);
            }
        const float hsum = fmaxf((h0 + h1) + h2, 0.f);   // ReLU

        const float4 wa = *(const float4*)&w2t[c][0];
        const float4 wb = *(const float4*)&w2t[c][4];
        const float  w8 = w2t[c][8];
        acc[0] = fmaf(wa.x, hsum, acc[0]);
        acc[1] = fmaf(wa.y, hsum, acc[1]);
        acc[2] = fmaf(wa.z, hsum, acc[2]);
        acc[3] = fmaf(wa.w, hsum, acc[3]);
        acc[4] = fmaf(wb.x, hsum, acc[4]);
        acc[5] = fmaf(wb.y, hsum, acc[5]);
        acc[6] = fmaf(wb.z, hsum, acc[6]);
        acc[7] = fmaf(wb.w, hsum, acc[7]);
        acc[8] = fmaf(w8,  hsum, acc[8]);
    }

    float* kr = kws + (size_t)(b * H_ + y) * TAPS * W_;
    #pragma unroll
    for (int t = 0; t < TAPS; ++t) kr[t * W_ + x] = acc[t];
}

// ============================================================================
// Kernel 2 (gate): out = h * sigmoid(sum_taps shifted(h) * kern)
// R11 structure (sliding window + LDS-staged kern) with the R12 change:
//   OCCUPANCY. R11 self-capped at launch_bounds(256,3) = 12 waves/CU (33%
//   measured) while VGPR was only 60. Falsified theory: L2 traffic cut 40%
//   in R11 moved time only 4% -> not traffic-bound; the limiter is in-flight
//   load concurrency, which scales with waves/CU (TLP the compiler can't
//   sink, unlike all my R7-R10 ILP attempts).
//   -> strips of 4 rows: 2048 blocks (8/CU available), launch_bounds(256,6)
//      = 24 waves/CU target; 6 x 18KB = 108KB LDS fits.
// ============================================================================
__global__ __launch_bounds__(256, 6)
void hsa_gate(const float* __restrict__ hin,
              const float* __restrict__ kws,
              float* __restrict__ out)
{
    __shared__ float ksh[2][TAPS][W_];   // 18 KB double-buffered kern rows

    const int tid = threadIdx.x;
    const int bid = blockIdx.x;          // 0..2047
    // bijective XCD swizzle: 2048 = 8 XCDs x 256; each XCD owns one batch.
    const int nb  = (bid & 7) * 256 + (bid >> 3);
    const int b     = nb >> 8;           // 0..7
    const int strip = (nb >> 2) & 63;    // 0..63
    const int cg    = nb & 3;            // 0..3
    const int Y     = strip * 4;

    const int lane = tid & 63;
    const int wv   = tid >> 6;           // 0..3
    const int x0   = lane * 4;
    const int c0   = cg * 16 + wv * 4;   // this wave's 4 channels

    const size_t plane = (size_t)H_ * W_;
    const float* hb = hin + ((size_t)b * C_ + c0) * plane;
    float*       ob = out + ((size_t)b * C_ + c0) * plane;
    const float* kbase = kws + (size_t)b * H_ * (TAPS * W_);

    const float lmask = (lane > 0)  ? 1.f : 0.f;
    const float rmask = (lane < 63) ? 1.f : 0.f;

    f32x4 win[3][4];        // 3-row h window x 4 channels

    // ---- prologue: h window + stage kern row Y into ksh[0] ----
    {
        const int ym = (Y > 0) ? (Y - 1) : 0;   // clamped; masked via kt
        #pragma unroll
        for (int i = 0; i < 4; ++i)
            win[0][i] = *(const f32x4*)(hb + i * plane + (size_t)ym      * W_ + x0);
        #pragma unroll
        for (int i = 0; i < 4; ++i)
            win[1][i] = *(const f32x4*)(hb + i * plane + (size_t)Y       * W_ + x0);
        #pragma unroll
        for (int i = 0; i < 4; ++i)
            win[2][i] = *(const f32x4*)(hb + i * plane + (size_t)(Y + 1) * W_ + x0);

        const float* kr = kbase + (size_t)Y * (TAPS * W_);
        #pragma unroll
        for (int t = 0; t < TAPS; ++t)
            ksh[0][t][tid] = kr[t * W_ + tid];   // 9 coalesced 1KB loads/block
    }
    __syncthreads();

    #pragma unroll
    for (int yy = 0; yy < 4; ++yy) {
        const int yg  = Y + yy;
        const int cur = yy & 1;

        // (a) next kern row -> registers (issued early, consumed after compute)
        float kst[TAPS];
        if (yy < 3) {
            const float* kr = kbase + (size_t)(yg + 1) * (TAPS * W_);
            #pragma unroll
            for (int t = 0; t < TAPS; ++t) kst[t] = kr[t * W_ + tid];
        }

        // next h row (enters window at end of this iter)
        f32x4 nxt[4];
        if (yy < 3) {
            const int yn = (yg + 2 < H_) ? (yg + 2) : (H_ - 1);
            #pragma unroll
            for (int i = 0; i < 4; ++i)
                nxt[i] = *(const f32x4*)(hb + i * plane + (size_t)yn * W_ + x0);
        }

        // (b) kt from LDS + fold boundary masks
        f32x4 kt[TAPS];
        #pragma unroll
        for (int t = 0; t < TAPS; ++t) kt[t] = *(const f32x4*)&ksh[cur][t][x0];

        const float m0 = (yg > 0)      ? 1.f : 0.f;
        const float m2 = (yg < H_ - 1) ? 1.f : 0.f;
        #pragma unroll
        for (int t = 0; t < 3; ++t) { kt[t] *= m0; kt[6 + t] *= m2; }
        kt[0].x *= lmask; kt[3].x *= lmask; kt[6].x *= lmask;
        kt[2].w *= rmask; kt[5].w *= rmask; kt[8].w *= rmask;

        // compute 4 channels (pure FMA + 2 shuffles per row)
        float sim[4][4];
        #pragma unroll
        for (int i = 0; i < 4; ++i)
            #pragma unroll
            for (int j = 0; j < 4; ++j) sim[i][j] = 0.f;

        #pragma unroll
        for (int r = 0; r < 3; ++r) {
            const int sl = (yy + r) % 3;          // compile-time after unroll
            const f32x4 k0 = kt[r * 3 + 0];
            const f32x4 k1 = kt[r * 3 + 1];
            const f32x4 k2 = kt[r * 3 + 2];
            #pragma unroll
            for (int i = 0; i < 4; ++i) {
                const f32x4 cv = win[sl][i];
                const float l  = __shfl_up(cv.w, 1);    // x0-1 (lane0 masked via kt)
                const float rr = __shfl_down(cv.x, 1);  // x0+4 (lane63 masked via kt)
                sim[i][0] = fmaf(l,    k0.x, fmaf(cv.x, k1.x, fmaf(cv.y, k2.x, sim[i][0])));
                sim[i][1] = fmaf(cv.x, k0.y, fmaf(cv.y, k1.y, fmaf(cv.z, k2.y, sim[i][1])));
                sim[i][2] = fmaf(cv.y, k0.z, fmaf(cv.z, k1.z, fmaf(cv.w, k2.z, sim[i][2])));
                sim[i][3] = fmaf(cv.z, k0.w, fmaf(cv.w, k1.w, fmaf(rr,   k2.w, sim[i][3])));
            }
        }

        // gate + store
        #pragma unroll
        for (int i = 0; i < 4; ++i) {
            const f32x4 ctr = win[(yy + 1) % 3][i];
            f32x4 o;
            o.x = ctr.x * __builtin_amdgcn_rcpf(1.f + __expf(-sim[i][0]));
            o.y = ctr.y * __builtin_amdgcn_rcpf(1.f + __expf(-sim[i][1]));
            o.z = ctr.z * __builtin_amdgcn_rcpf(1.f + __expf(-sim[i][2]));
            o.w = ctr.w * __builtin_amdgcn_rcpf(1.f + __expf(-sim[i][3]));
            *(f32x4*)(ob + i * plane + (size_t)yg * W_ + x0) = o;
        }

        // rotate h window
        if (yy < 3) {
            #pragma unroll
            for (int i = 0; i < 4; ++i) win[yy % 3][i] = nxt[i];
        }

        // (c) publish next kern row to the alternate LDS buffer, one barrier
        if (yy < 3) {
            #pragma unroll
            for (int t = 0; t < TAPS; ++t) ksh[cur ^ 1][t][tid] = kst[t];
            __syncthreads();
        }
    }
}

// ============================================================================
// Fallback: single fused kernel (used only if ws_size is too small)
// ============================================================================
__global__ __launch_bounds__(256, 4)
void hsa_fused(const float* __restrict__ lr,
               const float* __restrict__ hin,
               const float* __restrict__ w1,
               const float* __restrict__ b1,
               const float* __restrict__ w2,
               const float* __restrict__ b2,
               float* __restrict__ out)
{
    __shared__ float kernS[TAPS][W_];
    __shared__ float w2t[C_][12];

    const int tid = threadIdx.x;
    const int blk = blockIdx.x;
    const int b = blk / H_;
    const int y = blk % H_;

    for (int i = tid; i < TAPS * C_; i += 256) {
        const int t = i / C_;
        const int c = i % C_;
        w2t[c][t] = w2[i];
    }
    __syncthreads();

    {
        const int x = tid;
        float win[CIN][3][3];
        #pragma unroll
        for (int ci = 0; ci < CIN; ++ci)
            #pragma unroll
            for (int r = 0; r < 3; ++r) {
                const int yy = y + r - 1;
                const bool vy = (unsigned)yy < (unsigned)H_;
                const float* row = lr + ((size_t)(b * CIN + ci) * H_ + yy) * W_;
                win[ci][r][0] = (vy && x > 0)      ? row[x - 1] : 0.f;
                win[ci][r][1] = vy                  ? row[x]     : 0.f;
                win[ci][r][2] = (vy && x < W_ - 1) ? row[x + 1] : 0.f;
            }

        float acc[TAPS];
        #pragma unroll
        for (int t = 0; t < TAPS; ++t) acc[t] = b2[t];

        for (int c = 0; c < C_; ++c) {
            const float* wc = w1 + c * 27;
            float h0 = b1[c], h1 = 0.f, h2 = 0.f;
            #pragma unroll
            for (int r = 0; r < 3; ++r)
                #pragma unroll
                for (int j = 0; j < 3; ++j) {
                    h0 = fmaf(wc[(0 * 3 + r) * 3 + j], win[0][r][j], h0);
                    h1 = fmaf(wc[(1 * 3 + r) * 3 + j], win[1][r][j], h1);
                    h2 = fmaf(wc[(2 * 3 + r) * 3 + j], win[2][r][j], h2);
                }
            const float hsum = fmaxf((h0 + h1) + h2, 0.f);
            const float4 wa = *(const float4*)&w2t[c][0];
            const float4 wb = *(const float4*)&w2t[c][4];
            const float  w8 = w2t[c][8];
            acc[0] = fmaf(wa.x, hsum, acc[0]);
            acc[1] = fmaf(wa.y, hsum, acc[1]);
            acc[2] = fmaf(wa.z, hsum, acc[2]);
            acc[3] = fmaf(wa.w, hsum, acc[3]);
            acc[4] = fmaf(wb.x, hsum, acc[4]);
            acc[5] = fmaf(wb.y, hsum, acc[5]);
            acc[6] = fmaf(wb.z, hsum, acc[6]);
            acc[7] = fmaf(wb.w, hsum, acc[7]);
            acc[8] = fmaf(w8,  hsum, acc[8]);
        }
        #pragma unroll
        for (int t = 0; t < TAPS; ++t) kernS[t][x] = acc[t];
    }
    __syncthreads();

    const int lane = tid & 63;
    const int wav  = tid >> 6;
    const int x0   = lane * 4;

    float4 kt[TAPS];
    #pragma unroll
    for (int t = 0; t < TAPS; ++t) kt[t] = *(const float4*)&kernS[t][x0];

    #pragma unroll 4
    for (int cc = 0; cc < 16; ++cc) {
        const int c = wav * 16 + cc;
        const float* hb = hin + (size_t)(b * C_ + c) * H_ * W_;

        float4 rowv[3];
        float  lft[3], rgt[3];
        #pragma unroll
        for (int r = 0; r < 3; ++r) {
            const int yy = y + r - 1;
            const bool vy = (unsigned)yy < (unsigned)H_;
            float4 m;
            if (vy) m = *(const float4*)(hb + (size_t)yy * W_ + x0);
            else    m = make_float4(0.f, 0.f, 0.f, 0.f);
            rowv[r] = m;
            float l  = __shfl_up(m.w, 1);
            float rr = __shfl_down(m.x, 1);
            if (lane == 0)  l  = 0.f;
            if (lane == 63) rr = 0.f;
            lft[r] = l; rgt[r] = rr;
        }

        float sim0 = 0.f, sim1 = 0.f, sim2 = 0.f, sim3 = 0.f;
        #pragma unroll
        for (int r = 0; r < 3; ++r) {
            const float w6_0 = lft[r];
            const float w6_1 = rowv[r].x;
            const float w6_2 = rowv[r].y;
            const float w6_3 = rowv[r].z;
            const float w6_4 = rowv[r].w;
            const float w6_5 = rgt[r];
            { const float4 k4 = kt[r*3+0];
              sim0 = fmaf(w6_0, k4.x, sim0); sim1 = fmaf(w6_1, k4.y, sim1);
              sim2 = fmaf(w6_2, k4.z, sim2); sim3 = fmaf(w6_3, k4.w, sim3); }
            { const float4 k4 = kt[r*3+1];
              sim0 = fmaf(w6_1, k4.x, sim0); sim1 = fmaf(w6_2, k4.y, sim1);
              sim2 = fmaf(w6_3, k4.z, sim2); sim3 = fmaf(w6_4, k4.w, sim3); }
            { const float4 k4 = kt[r*3+2];
              sim0 = fmaf(w6_2, k4.x, sim0); sim1 = fmaf(w6_3, k4.y, sim1);
              sim2 = fmaf(w6_4, k4.z, sim2); sim3 = fmaf(w6_5, k4.w, sim3); }
        }

        float4 o;
        o.x = rowv[1].x * __builtin_amdgcn_rcpf(1.f + __expf(-sim0));
        o.y = rowv[1].y * __builtin_amdgcn_rcpf(1.f + __expf(-sim1));
        o.z = rowv[1].z * __builtin_amdgcn_rcpf(1.f + __expf(-sim2));
        o.w = rowv[1].w * __builtin_amdgcn_rcpf(1.f + __expf(-sim3));
        *(float4*)(out + ((size_t)(b * C_ + c) * H_ + y) * W_ + x0) = o;
    }
}

extern "C" void kernel_launch(void* const* d_in, const int* in_sizes, int n_in,
                              void* d_out, int out_size, void* d_ws, size_t ws_size,
                              hipStream_t stream) {
    const float* lr  = (const float*)d_in[0];  // [8,3,256,256]
    const float* hin = (const float*)d_in[1];  // [8,64,256,256]
    const float* w1  = (const float*)d_in[2];  // [64,3,3,3]
    const float* b1  = (const float*)d_in[3];  // [64]
    const float* w2  = (const float*)d_in[4];  // [9,64,1,1]
    const float* b2  = (const float*)d_in[5];  // [9]
    float* out = (float*)d_out;                // [8,64,256,256]

    const size_t kern_bytes = (size_t)B_ * H_ * TAPS * W_ * sizeof(float);

    if (ws_size >= kern_bytes) {
        float* kws = (float*)d_ws;
        hipLaunchKernelGGL(hsa_kern, dim3(B_ * H_), dim3(256), 0, stream,
                           lr, w1, b1, w2, b2, kws);
        // 8 batches x 64 strips x 4 channel-groups = 2048 blocks
        hipLaunchKernelGGL(hsa_gate, dim3(2048), dim3(256), 0, stream,
                           hin, kws, out);
    } else {
        hipLaunchKernelGGL(hsa_fused, dim3(B_ * H_), dim3(256), 0, stream,
                           lr, hin, w1, b1, w2, b2, out);
    }
}

// Round 13
// 109.818 us; speedup vs baseline: 1.6194x; 1.6194x over previous
//
#include <hip/hip_runtime.h>
#include <hip/hip_bf16.h>
#include <math.h>

// Problem constants (from reference setup_inputs)
constexpr int B_  = 8;
constexpr int CIN = 3;
constexpr int C_  = 64;
constexpr int H_  = 256;
constexpr int W_  = 256;
constexpr int TAPS = 9;   // K*K, K=3

typedef float f32x4 __attribute__((ext_vector_type(4)));

// ============================================================================
// Kernel 1 (compute-bound, ~VALU roofline): kern = conv1x1(relu(conv3x3(lr)))
// ============================================================================
__global__ __launch_bounds__(256, 4)
void hsa_kern(const float* __restrict__ lr,
              const float* __restrict__ w1,
              const float* __restrict__ b1,
              const float* __restrict__ w2,
              const float* __restrict__ b2,
              float* __restrict__ kws)
{
    __shared__ float w2t[C_][12];       // transposed 1x1 weights

    const int tid = threadIdx.x;
    const int blk = blockIdx.x;         // 0 .. B_*H_-1
    const int b = blk / H_;
    const int y = blk % H_;

    for (int i = tid; i < TAPS * C_; i += 256) {
        const int t = i / C_;
        const int c = i % C_;
        w2t[c][t] = w2[i];
    }
    __syncthreads();

    const int x = tid;                  // 0..255
    float win[CIN][3][3];
    #pragma unroll
    for (int ci = 0; ci < CIN; ++ci) {
        #pragma unroll
        for (int r = 0; r < 3; ++r) {
            const int yy = y + r - 1;
            const bool vy = (unsigned)yy < (unsigned)H_;
            const float* row = lr + ((size_t)(b * CIN + ci) * H_ + yy) * W_;
            win[ci][r][0] = (vy && x > 0)       ? row[x - 1] : 0.f;
            win[ci][r][1] = vy                   ? row[x]     : 0.f;
            win[ci][r][2] = (vy && x < W_ - 1)  ? row[x + 1] : 0.f;
        }
    }

    float acc[TAPS];
    #pragma unroll
    for (int t = 0; t < TAPS; ++t) acc[t] = b2[t];

    for (int c = 0; c < C_; ++c) {
        const float* wc = w1 + c * 27;
        float h0 = b1[c], h1 = 0.f, h2 = 0.f;
        #pragma unroll
        for (int r = 0; r < 3; ++r)
            #pragma unroll
            for (int j = 0; j < 3; ++j) {
                h0 = fmaf(wc[(0 * 3 + r) * 3 + j], win[0][r][j], h0);
                h1 = fmaf(wc[(1 * 3 + r) * 3 + j], win[1][r][j], h1);
                h2 = fmaf(wc[(2 * 3 + r) * 3 + j], win[2][r][j], h2);
            }
        const float hsum = fmaxf((h0 + h1) + h2, 0.f);   // ReLU

        const float4 wa = *(const float4*)&w2t[c][0];
        const float4 wb = *(const float4*)&w2t[c][4];
        const float  w8 = w2t[c][8];
        acc[0] = fmaf(wa.x, hsum, acc[0]);
        acc[1] = fmaf(wa.y, hsum, acc[1]);
        acc[2] = fmaf(wa.z, hsum, acc[2]);
        acc[3] = fmaf(wa.w, hsum, acc[3]);
        acc[4] = fmaf(wb.x, hsum, acc[4]);
        acc[5] = fmaf(wb.y, hsum, acc[5]);
        acc[6] = fmaf(wb.z, hsum, acc[6]);
        acc[7] = fmaf(wb.w, hsum, acc[7]);
        acc[8] = fmaf(w8,  hsum, acc[8]);
    }

    float* kr = kws + (size_t)(b * H_ + y) * TAPS * W_;
    #pragma unroll
    for (int t = 0; t < TAPS; ++t) kr[t * W_ + x] = acc[t];
}

// ============================================================================
// Kernel 2 (gate): out = h * sigmoid(sum_taps shifted(h) * kern)
// R11 structure (8-row strips: traffic-optimal halo reuse; LDS-staged kern)
// with the R13 change: MORE BLOCKS/CU WITHOUT TRAFFIC COST.
//   R12 lesson: time tracks HBM bytes at a ~3 TB/s pattern wall; 4-row
//   strips inflated bytes 2.2x -> regression. R11 lesson: occupancy was
//   GRID-limited (1024 blocks = 4/CU available, ~2.75 avg).
//   -> split channels finer instead of rows: 8 ch/block (wave owns 2),
//      grid = 8b x 32strips x 8cg = 2048 blocks = 8/CU; LDS 8x18KB = 144KB
//      fits; h traffic identical to R11; kern re-read doubles but is
//      L3-resident (19 MB).
// ============================================================================
__global__ __launch_bounds__(256, 8)
void hsa_gate(const float* __restrict__ hin,
              const float* __restrict__ kws,
              float* __restrict__ out)
{
    __shared__ float ksh[2][TAPS][W_];   // 18 KB double-buffered kern rows

    const int tid = threadIdx.x;
    const int bid = blockIdx.x;          // 0..2047
    // bijective XCD swizzle: 2048 = 8 XCDs x 256; each XCD owns one batch.
    const int nb  = (bid & 7) * 256 + (bid >> 3);
    const int b     = nb >> 8;           // 0..7
    const int strip = (nb >> 3) & 31;    // 0..31 (8-row strips)
    const int cg    = nb & 7;            // 0..7 (consecutive nb share kern rows)
    const int Y     = strip * 8;

    const int lane = tid & 63;
    const int wv   = tid >> 6;           // 0..3
    const int x0   = lane * 4;
    const int c0   = cg * 8 + wv * 2;    // this wave's 2 channels

    const size_t plane = (size_t)H_ * W_;
    const float* hb = hin + ((size_t)b * C_ + c0) * plane;
    float*       ob = out + ((size_t)b * C_ + c0) * plane;
    const float* kbase = kws + (size_t)b * H_ * (TAPS * W_);

    const float lmask = (lane > 0)  ? 1.f : 0.f;
    const float rmask = (lane < 63) ? 1.f : 0.f;

    f32x4 win[3][2];        // 3-row h window x 2 channels

    // ---- prologue: h window + stage kern row Y into ksh[0] ----
    {
        const int ym = (Y > 0) ? (Y - 1) : 0;   // clamped; masked via kt
        #pragma unroll
        for (int i = 0; i < 2; ++i)
            win[0][i] = *(const f32x4*)(hb + i * plane + (size_t)ym      * W_ + x0);
        #pragma unroll
        for (int i = 0; i < 2; ++i)
            win[1][i] = *(const f32x4*)(hb + i * plane + (size_t)Y       * W_ + x0);
        #pragma unroll
        for (int i = 0; i < 2; ++i)
            win[2][i] = *(const f32x4*)(hb + i * plane + (size_t)(Y + 1) * W_ + x0);

        const float* kr = kbase + (size_t)Y * (TAPS * W_);
        #pragma unroll
        for (int t = 0; t < TAPS; ++t)
            ksh[0][t][tid] = kr[t * W_ + tid];   // 9 coalesced 1KB loads/block
    }
    __syncthreads();

    #pragma unroll
    for (int yy = 0; yy < 8; ++yy) {
        const int yg  = Y + yy;
        const int cur = yy & 1;

        // (a) next kern row -> registers (issued early, consumed after compute)
        float kst[TAPS];
        if (yy < 7) {
            const float* kr = kbase + (size_t)(yg + 1) * (TAPS * W_);
            #pragma unroll
            for (int t = 0; t < TAPS; ++t) kst[t] = kr[t * W_ + tid];
        }

        // next h row (enters window at end of this iter)
        f32x4 nxt[2];
        if (yy < 7) {
            const int yn = (yg + 2 < H_) ? (yg + 2) : (H_ - 1);
            #pragma unroll
            for (int i = 0; i < 2; ++i)
                nxt[i] = *(const f32x4*)(hb + i * plane + (size_t)yn * W_ + x0);
        }

        // (b) kt from LDS + fold boundary masks
        f32x4 kt[TAPS];
        #pragma unroll
        for (int t = 0; t < TAPS; ++t) kt[t] = *(const f32x4*)&ksh[cur][t][x0];

        const float m0 = (yg > 0)      ? 1.f : 0.f;
        const float m2 = (yg < H_ - 1) ? 1.f : 0.f;
        #pragma unroll
        for (int t = 0; t < 3; ++t) { kt[t] *= m0; kt[6 + t] *= m2; }
        kt[0].x *= lmask; kt[3].x *= lmask; kt[6].x *= lmask;
        kt[2].w *= rmask; kt[5].w *= rmask; kt[8].w *= rmask;

        // compute 2 channels (pure FMA + 2 shuffles per row-channel)
        float sim[2][4];
        #pragma unroll
        for (int i = 0; i < 2; ++i)
            #pragma unroll
            for (int j = 0; j < 4; ++j) sim[i][j] = 0.f;

        #pragma unroll
        for (int r = 0; r < 3; ++r) {
            const int sl = (yy + r) % 3;          // compile-time after unroll
            const f32x4 k0 = kt[r * 3 + 0];
            const f32x4 k1 = kt[r * 3 + 1];
            const f32x4 k2 = kt[r * 3 + 2];
            #pragma unroll
            for (int i = 0; i < 2; ++i) {
                const f32x4 cv = win[sl][i];
                const float l  = __shfl_up(cv.w, 1);    // x0-1 (lane0 masked via kt)
                const float rr = __shfl_down(cv.x, 1);  // x0+4 (lane63 masked via kt)
                sim[i][0] = fmaf(l,    k0.x, fmaf(cv.x, k1.x, fmaf(cv.y, k2.x, sim[i][0])));
                sim[i][1] = fmaf(cv.x, k0.y, fmaf(cv.y, k1.y, fmaf(cv.z, k2.y, sim[i][1])));
                sim[i][2] = fmaf(cv.y, k0.z, fmaf(cv.z, k1.z, fmaf(cv.w, k2.z, sim[i][2])));
                sim[i][3] = fmaf(cv.z, k0.w, fmaf(cv.w, k1.w, fmaf(rr,   k2.w, sim[i][3])));
            }
        }

        // gate + store
        #pragma unroll
        for (int i = 0; i < 2; ++i) {
            const f32x4 ctr = win[(yy + 1) % 3][i];
            f32x4 o;
            o.x = ctr.x * __builtin_amdgcn_rcpf(1.f + __expf(-sim[i][0]));
            o.y = ctr.y * __builtin_amdgcn_rcpf(1.f + __expf(-sim[i][1]));
            o.z = ctr.z * __builtin_amdgcn_rcpf(1.f + __expf(-sim[i][2]));
            o.w = ctr.w * __builtin_amdgcn_rcpf(1.f + __expf(-sim[i][3]));
            *(f32x4*)(ob + i * plane + (size_t)yg * W_ + x0) = o;
        }

        // rotate h window
        if (yy < 7) {
            #pragma unroll
            for (int i = 0; i < 2; ++i) win[yy % 3][i] = nxt[i];
        }

        // (c) publish next kern row to the alternate LDS buffer, one barrier
        if (yy < 7) {
            #pragma unroll
            for (int t = 0; t < TAPS; ++t) ksh[cur ^ 1][t][tid] = kst[t];
            __syncthreads();
        }
    }
}

// ============================================================================
// Fallback: single fused kernel (used only if ws_size is too small)
// ============================================================================
__global__ __launch_bounds__(256, 4)
void hsa_fused(const float* __restrict__ lr,
               const float* __restrict__ hin,
               const float* __restrict__ w1,
               const float* __restrict__ b1,
               const float* __restrict__ w2,
               const float* __restrict__ b2,
               float* __restrict__ out)
{
    __shared__ float kernS[TAPS][W_];
    __shared__ float w2t[C_][12];

    const int tid = threadIdx.x;
    const int blk = blockIdx.x;
    const int b = blk / H_;
    const int y = blk % H_;

    for (int i = tid; i < TAPS * C_; i += 256) {
        const int t = i / C_;
        const int c = i % C_;
        w2t[c][t] = w2[i];
    }
    __syncthreads();

    {
        const int x = tid;
        float win[CIN][3][3];
        #pragma unroll
        for (int ci = 0; ci < CIN; ++ci)
            #pragma unroll
            for (int r = 0; r < 3; ++r) {
                const int yy = y + r - 1;
                const bool vy = (unsigned)yy < (unsigned)H_;
                const float* row = lr + ((size_t)(b * CIN + ci) * H_ + yy) * W_;
                win[ci][r][0] = (vy && x > 0)      ? row[x - 1] : 0.f;
                win[ci][r][1] = vy                  ? row[x]     : 0.f;
                win[ci][r][2] = (vy && x < W_ - 1) ? row[x + 1] : 0.f;
            }

        float acc[TAPS];
        #pragma unroll
        for (int t = 0; t < TAPS; ++t) acc[t] = b2[t];

        for (int c = 0; c < C_; ++c) {
            const float* wc = w1 + c * 27;
            float h0 = b1[c], h1 = 0.f, h2 = 0.f;
            #pragma unroll
            for (int r = 0; r < 3; ++r)
                #pragma unroll
                for (int j = 0; j < 3; ++j) {
                    h0 = fmaf(wc[(0 * 3 + r) * 3 + j], win[0][r][j], h0);
                    h1 = fmaf(wc[(1 * 3 + r) * 3 + j], win[1][r][j], h1);
                    h2 = fmaf(wc[(2 * 3 + r) * 3 + j], win[2][r][j], h2);
                }
            const float hsum = fmaxf((h0 + h1) + h2, 0.f);
            const float4 wa = *(const float4*)&w2t[c][0];
            const float4 wb = *(const float4*)&w2t[c][4];
            const float  w8 = w2t[c][8];
            acc[0] = fmaf(wa.x, hsum, acc[0]);
            acc[1] = fmaf(wa.y, hsum, acc[1]);
            acc[2] = fmaf(wa.z, hsum, acc[2]);
            acc[3] = fmaf(wa.w, hsum, acc[3]);
            acc[4] = fmaf(wb.x, hsum, acc[4]);
            acc[5] = fmaf(wb.y, hsum, acc[5]);
            acc[6] = fmaf(wb.z, hsum, acc[6]);
            acc[7] = fmaf(wb.w, hsum, acc[7]);
            acc[8] = fmaf(w8,  hsum, acc[8]);
        }
        #pragma unroll
        for (int t = 0; t < TAPS; ++t) kernS[t][x] = acc[t];
    }
    __syncthreads();

    const int lane = tid & 63;
    const int wav  = tid >> 6;
    const int x0   = lane * 4;

    float4 kt[TAPS];
    #pragma unroll
    for (int t = 0; t < TAPS; ++t) kt[t] = *(const float4*)&kernS[t][x0];

    #pragma unroll 4
    for (int cc = 0; cc < 16; ++cc) {
        const int c = wav * 16 + cc;
        const float* hb = hin + (size_t)(b * C_ + c) * H_ * W_;

        float4 rowv[3];
        float  lft[3], rgt[3];
        #pragma unroll
        for (int r = 0; r < 3; ++r) {
            const int yy = y + r - 1;
            const bool vy = (unsigned)yy < (unsigned)H_;
            float4 m;
            if (vy) m = *(const float4*)(hb + (size_t)yy * W_ + x0);
            else    m = make_float4(0.f, 0.f, 0.f, 0.f);
            rowv[r] = m;
            float l  = __shfl_up(m.w, 1);
            float rr = __shfl_down(m.x, 1);
            if (lane == 0)  l  = 0.f;
            if (lane == 63) rr = 0.f;
            lft[r] = l; rgt[r] = rr;
        }

        float sim0 = 0.f, sim1 = 0.f, sim2 = 0.f, sim3 = 0.f;
        #pragma unroll
        for (int r = 0; r < 3; ++r) {
            const float w6_0 = lft[r];
            const float w6_1 = rowv[r].x;
            const float w6_2 = rowv[r].y;
            const float w6_3 = rowv[r].z;
            const float w6_4 = rowv[r].w;
            const float w6_5 = rgt[r];
            { const float4 k4 = kt[r*3+0];
              sim0 = fmaf(w6_0, k4.x, sim0); sim1 = fmaf(w6_1, k4.y, sim1);
              sim2 = fmaf(w6_2, k4.z, sim2); sim3 = fmaf(w6_3, k4.w, sim3); }
            { const float4 k4 = kt[r*3+1];
              sim0 = fmaf(w6_1, k4.x, sim0); sim1 = fmaf(w6_2, k4.y, sim1);
              sim2 = fmaf(w6_3, k4.z, sim2); sim3 = fmaf(w6_4, k4.w, sim3); }
            { const float4 k4 = kt[r*3+2];
              sim0 = fmaf(w6_2, k4.x, sim0); sim1 = fmaf(w6_3, k4.y, sim1);
              sim2 = fmaf(w6_4, k4.z, sim2); sim3 = fmaf(w6_5, k4.w, sim3); }
        }

        float4 o;
        o.x = rowv[1].x * __builtin_amdgcn_rcpf(1.f + __expf(-sim0));
        o.y = rowv[1].y * __builtin_amdgcn_rcpf(1.f + __expf(-sim1));
        o.z = rowv[1].z * __builtin_amdgcn_rcpf(1.f + __expf(-sim2));
        o.w = rowv[1].w * __builtin_amdgcn_rcpf(1.f + __expf(-sim3));
        *(float4*)(out + ((size_t)(b * C_ + c) * H_ + y) * W_ + x0) = o;
    }
}

extern "C" void kernel_launch(void* const* d_in, const int* in_sizes, int n_in,
                              void* d_out, int out_size, void* d_ws, size_t ws_size,
                              hipStream_t stream) {
    const float* lr  = (const float*)d_in[0];  // [8,3,256,256]
    const float* hin = (const float*)d_in[1];  // [8,64,256,256]
    const float* w1  = (const float*)d_in[2];  // [64,3,3,3]
    const float* b1  = (const float*)d_in[3];  // [64]
    const float* w2  = (const float*)d_in[4];  // [9,64,1,1]
    const float* b2  = (const float*)d_in[5];  // [9]
    float* out = (float*)d_out;                // [8,64,256,256]

    const size_t kern_bytes = (size_t)B_ * H_ * TAPS * W_ * sizeof(float);

    if (ws_size >= kern_bytes) {
        float* kws = (float*)d_ws;
        hipLaunchKernelGGL(hsa_kern, dim3(B_ * H_), dim3(256), 0, stream,
                           lr, w1, b1, w2, b2, kws);
        // 8 batches x 32 strips(8 rows) x 8 channel-groups = 2048 blocks
        hipLaunchKernelGGL(hsa_gate, dim3(2048), dim3(256), 0, stream,
                           hin, kws, out);
    } else {
        hipLaunchKernelGGL(hsa_fused, dim3(B_ * H_), dim3(256), 0, stream,
                           lr, hin, w1, b1, w2, b2, out);
    }
}

// Round 14
// 93.740 us; speedup vs baseline: 1.8972x; 1.1715x over previous
//
#include <hip/hip_runtime.h>
#include <hip/hip_bf16.h>
#include <math.h>

// Problem constants (from reference setup_inputs)
constexpr int B_  = 8;
constexpr int CIN = 3;
constexpr int C_  = 64;
constexpr int H_  = 256;
constexpr int W_  = 256;
constexpr int TAPS = 9;   // K*K, K=3
constexpr int KROW = TAPS * W_ / 2;   // u32 words per bf16 kern row (1152)

typedef float f32x4 __attribute__((ext_vector_type(4)));

static __device__ __forceinline__ unsigned short f2bf(float f) {
    // RNE f32 -> bf16 (no NaN handling needed for this data)
    unsigned int u = __float_as_uint(f);
    unsigned int r = (u + 0x7fffu + ((u >> 16) & 1u)) >> 16;
    return (unsigned short)r;
}

// ============================================================================
// Kernel 1 (compute-bound, ~VALU roofline): kern = conv1x1(relu(conv3x3(lr)))
// Output kws in BF16 (R14): halves kern HBM+L2 bytes; gate expands exactly
// via bit-shift. Error budget: measured 0.0156 of 0.101 threshold.
// ============================================================================
__global__ __launch_bounds__(256, 4)
void hsa_kern(const float* __restrict__ lr,
              const float* __restrict__ w1,
              const float* __restrict__ b1,
              const float* __restrict__ w2,
              const float* __restrict__ b2,
              unsigned short* __restrict__ kws)
{
    __shared__ float w2t[C_][12];       // transposed 1x1 weights

    const int tid = threadIdx.x;
    const int blk = blockIdx.x;         // 0 .. B_*H_-1
    const int b = blk / H_;
    const int y = blk % H_;

    for (int i = tid; i < TAPS * C_; i += 256) {
        const int t = i / C_;
        const int c = i % C_;
        w2t[c][t] = w2[i];
    }
    __syncthreads();

    const int x = tid;                  // 0..255
    float win[CIN][3][3];
    #pragma unroll
    for (int ci = 0; ci < CIN; ++ci) {
        #pragma unroll
        for (int r = 0; r < 3; ++r) {
            const int yy = y + r - 1;
            const bool vy = (unsigned)yy < (unsigned)H_;
            const float* row = lr + ((size_t)(b * CIN + ci) * H_ + yy) * W_;
            win[ci][r][0] = (vy && x > 0)       ? row[x - 1] : 0.f;
            win[ci][r][1] = vy                   ? row[x]     : 0.f;
            win[ci][r][2] = (vy && x < W_ - 1)  ? row[x + 1] : 0.f;
        }
    }

    float acc[TAPS];
    #pragma unroll
    for (int t = 0; t < TAPS; ++t) acc[t] = b2[t];

    for (int c = 0; c < C_; ++c) {
        const float* wc = w1 + c * 27;
        float h0 = b1[c], h1 = 0.f, h2 = 0.f;
        #pragma unroll
        for (int r = 0; r < 3; ++r)
            #pragma unroll
            for (int j = 0; j < 3; ++j) {
                h0 = fmaf(wc[(0 * 3 + r) * 3 + j], win[0][r][j], h0);
                h1 = fmaf(wc[(1 * 3 + r) * 3 + j], win[1][r][j], h1);
                h2 = fmaf(wc[(2 * 3 + r) * 3 + j], win[2][r][j], h2);
            }
        const float hsum = fmaxf((h0 + h1) + h2, 0.f);   // ReLU

        const float4 wa = *(const float4*)&w2t[c][0];
        const float4 wb = *(const float4*)&w2t[c][4];
        const float  w8 = w2t[c][8];
        acc[0] = fmaf(wa.x, hsum, acc[0]);
        acc[1] = fmaf(wa.y, hsum, acc[1]);
        acc[2] = fmaf(wa.z, hsum, acc[2]);
        acc[3] = fmaf(wa.w, hsum, acc[3]);
        acc[4] = fmaf(wb.x, hsum, acc[4]);
        acc[5] = fmaf(wb.y, hsum, acc[5]);
        acc[6] = fmaf(wb.z, hsum, acc[6]);
        acc[7] = fmaf(wb.w, hsum, acc[7]);
        acc[8] = fmaf(w8,  hsum, acc[8]);
    }

    unsigned short* kr = kws + (size_t)(b * H_ + y) * (TAPS * W_);
    #pragma unroll
    for (int t = 0; t < TAPS; ++t) kr[t * W_ + x] = f2bf(acc[t]);
}

// ============================================================================
// Kernel 2 (gate): out = h * sigmoid(sum_taps shifted(h) * kern)
// R11 structure EXACTLY (byte-optimal: 8-row strips, 16ch/block, 1024 blocks,
// sliding h window, LDS-staged double-buffered kern, masks folded into kt)
// with two byte/instruction cuts (R14):
//  - kws is BF16: kern HBM/L2 bytes halved; expansion = 2 bit-ops per value.
//  - staging vectorized: 5 u32 flat loads + 5 flat ds_writes per thread/iter
//    (was 9 scalar loads + 9 scalar ds_writes) -> 4x fewer kern VMEM insts.
// Rationale: R13 proved the pattern saturates ~3.1-3.2 TB/s (2x occupancy ->
// +9% BW); time tracks bytes, so cut bytes.
// ============================================================================
__global__ __launch_bounds__(256, 3)
void hsa_gate(const float* __restrict__ hin,
              const unsigned short* __restrict__ kws,
              float* __restrict__ out)
{
    __shared__ unsigned int ksh[2][KROW];   // 2 x 4.6 KB bf16 kern rows

    const int tid = threadIdx.x;
    const int bid = blockIdx.x;          // 0..1023
    // bijective XCD swizzle: 1024 = 8 XCDs x 128; each XCD owns one batch.
    const int nb  = (bid & 7) * 128 + (bid >> 3);
    const int b     = nb >> 7;           // 0..7
    const int strip = (nb >> 2) & 31;    // 0..31
    const int cg    = nb & 3;            // 0..3
    const int Y     = strip * 8;

    const int lane = tid & 63;
    const int wv   = tid >> 6;           // 0..3
    const int x0   = lane * 4;
    const int c0   = cg * 16 + wv * 4;   // this wave's 4 channels

    const size_t plane = (size_t)H_ * W_;
    const float* hb = hin + ((size_t)b * C_ + c0) * plane;
    float*       ob = out + ((size_t)b * C_ + c0) * plane;
    const unsigned int* kbase = (const unsigned int*)kws + (size_t)b * H_ * KROW;

    const float lmask = (lane > 0)  ? 1.f : 0.f;
    const float rmask = (lane < 63) ? 1.f : 0.f;

    f32x4 win[3][4];        // 3-row h window x 4 channels

    // ---- prologue: h window + stage kern row Y into ksh[0] ----
    {
        const int ym = (Y > 0) ? (Y - 1) : 0;   // clamped; masked via kt
        #pragma unroll
        for (int i = 0; i < 4; ++i)
            win[0][i] = *(const f32x4*)(hb + i * plane + (size_t)ym      * W_ + x0);
        #pragma unroll
        for (int i = 0; i < 4; ++i)
            win[1][i] = *(const f32x4*)(hb + i * plane + (size_t)Y       * W_ + x0);
        #pragma unroll
        for (int i = 0; i < 4; ++i)
            win[2][i] = *(const f32x4*)(hb + i * plane + (size_t)(Y + 1) * W_ + x0);

        const unsigned int* kr = kbase + (size_t)Y * KROW;
        #pragma unroll
        for (int i = 0; i < 5; ++i) {
            const int idx = tid + i * 256;
            if (idx < KROW) ksh[0][idx] = kr[idx];
        }
    }
    __syncthreads();

    #pragma unroll
    for (int yy = 0; yy < 8; ++yy) {
        const int yg  = Y + yy;
        const int cur = yy & 1;

        // (a) next kern row -> registers (issued early, consumed after compute)
        unsigned int kst[5];
        if (yy < 7) {
            const unsigned int* kr = kbase + (size_t)(yg + 1) * KROW;
            #pragma unroll
            for (int i = 0; i < 5; ++i) {
                const int idx = tid + i * 256;
                kst[i] = (idx < KROW) ? kr[idx] : 0u;
            }
        }

        // next h row (enters window at end of this iter)
        f32x4 nxt[4];
        if (yy < 7) {
            const int yn = (yg + 2 < H_) ? (yg + 2) : (H_ - 1);
            #pragma unroll
            for (int i = 0; i < 4; ++i)
                nxt[i] = *(const f32x4*)(hb + i * plane + (size_t)yn * W_ + x0);
        }

        // (b) kt from LDS (bf16 pairs -> f32 via bit ops, exact) + fold masks
        f32x4 kt[TAPS];
        #pragma unroll
        for (int t = 0; t < TAPS; ++t) {
            const unsigned int w0 = ksh[cur][t * 128 + lane * 2];
            const unsigned int w1 = ksh[cur][t * 128 + lane * 2 + 1];
            kt[t].x = __uint_as_float(w0 << 16);
            kt[t].y = __uint_as_float(w0 & 0xffff0000u);
            kt[t].z = __uint_as_float(w1 << 16);
            kt[t].w = __uint_as_float(w1 & 0xffff0000u);
        }

        const float m0 = (yg > 0)      ? 1.f : 0.f;
        const float m2 = (yg < H_ - 1) ? 1.f : 0.f;
        #pragma unroll
        for (int t = 0; t < 3; ++t) { kt[t] *= m0; kt[6 + t] *= m2; }
        kt[0].x *= lmask; kt[3].x *= lmask; kt[6].x *= lmask;
        kt[2].w *= rmask; kt[5].w *= rmask; kt[8].w *= rmask;

        // compute 4 channels (pure FMA + 2 shuffles per row-channel)
        float sim[4][4];
        #pragma unroll
        for (int i = 0; i < 4; ++i)
            #pragma unroll
            for (int j = 0; j < 4; ++j) sim[i][j] = 0.f;

        #pragma unroll
        for (int r = 0; r < 3; ++r) {
            const int sl = (yy + r) % 3;          // compile-time after unroll
            const f32x4 k0 = kt[r * 3 + 0];
            const f32x4 k1 = kt[r * 3 + 1];
            const f32x4 k2 = kt[r * 3 + 2];
            #pragma unroll
            for (int i = 0; i < 4; ++i) {
                const f32x4 cv = win[sl][i];
                const float l  = __shfl_up(cv.w, 1);    // x0-1 (lane0 masked via kt)
                const float rr = __shfl_down(cv.x, 1);  // x0+4 (lane63 masked via kt)
                sim[i][0] = fmaf(l,    k0.x, fmaf(cv.x, k1.x, fmaf(cv.y, k2.x, sim[i][0])));
                sim[i][1] = fmaf(cv.x, k0.y, fmaf(cv.y, k1.y, fmaf(cv.z, k2.y, sim[i][1])));
                sim[i][2] = fmaf(cv.y, k0.z, fmaf(cv.z, k1.z, fmaf(cv.w, k2.z, sim[i][2])));
                sim[i][3] = fmaf(cv.z, k0.w, fmaf(cv.w, k1.w, fmaf(rr,   k2.w, sim[i][3])));
            }
        }

        // gate + store
        #pragma unroll
        for (int i = 0; i < 4; ++i) {
            const f32x4 ctr = win[(yy + 1) % 3][i];
            f32x4 o;
            o.x = ctr.x * __builtin_amdgcn_rcpf(1.f + __expf(-sim[i][0]));
            o.y = ctr.y * __builtin_amdgcn_rcpf(1.f + __expf(-sim[i][1]));
            o.z = ctr.z * __builtin_amdgcn_rcpf(1.f + __expf(-sim[i][2]));
            o.w = ctr.w * __builtin_amdgcn_rcpf(1.f + __expf(-sim[i][3]));
            *(f32x4*)(ob + i * plane + (size_t)yg * W_ + x0) = o;
        }

        // rotate h window
        if (yy < 7) {
            #pragma unroll
            for (int i = 0; i < 4; ++i) win[yy % 3][i] = nxt[i];
        }

        // (c) publish next kern row to the alternate LDS buffer, one barrier
        if (yy < 7) {
            #pragma unroll
            for (int i = 0; i < 5; ++i) {
                const int idx = tid + i * 256;
                if (idx < KROW) ksh[cur ^ 1][idx] = kst[i];
            }
            __syncthreads();
        }
    }
}

// ============================================================================
// Fallback: single fused kernel (used only if ws_size is too small)
// ============================================================================
__global__ __launch_bounds__(256, 4)
void hsa_fused(const float* __restrict__ lr,
               const float* __restrict__ hin,
               const float* __restrict__ w1,
               const float* __restrict__ b1,
               const float* __restrict__ w2,
               const float* __restrict__ b2,
               float* __restrict__ out)
{
    __shared__ float kernS[TAPS][W_];
    __shared__ float w2t[C_][12];

    const int tid = threadIdx.x;
    const int blk = blockIdx.x;
    const int b = blk / H_;
    const int y = blk % H_;

    for (int i = tid; i < TAPS * C_; i += 256) {
        const int t = i / C_;
        const int c = i % C_;
        w2t[c][t] = w2[i];
    }
    __syncthreads();

    {
        const int x = tid;
        float win[CIN][3][3];
        #pragma unroll
        for (int ci = 0; ci < CIN; ++ci)
            #pragma unroll
            for (int r = 0; r < 3; ++r) {
                const int yy = y + r - 1;
                const bool vy = (unsigned)yy < (unsigned)H_;
                const float* row = lr + ((size_t)(b * CIN + ci) * H_ + yy) * W_;
                win[ci][r][0] = (vy && x > 0)      ? row[x - 1] : 0.f;
                win[ci][r][1] = vy                  ? row[x]     : 0.f;
                win[ci][r][2] = (vy && x < W_ - 1) ? row[x + 1] : 0.f;
            }

        float acc[TAPS];
        #pragma unroll
        for (int t = 0; t < TAPS; ++t) acc[t] = b2[t];

        for (int c = 0; c < C_; ++c) {
            const float* wc = w1 + c * 27;
            float h0 = b1[c], h1 = 0.f, h2 = 0.f;
            #pragma unroll
            for (int r = 0; r < 3; ++r)
                #pragma unroll
                for (int j = 0; j < 3; ++j) {
                    h0 = fmaf(wc[(0 * 3 + r) * 3 + j], win[0][r][j], h0);
                    h1 = fmaf(wc[(1 * 3 + r) * 3 + j], win[1][r][j], h1);
                    h2 = fmaf(wc[(2 * 3 + r) * 3 + j], win[2][r][j], h2);
                }
            const float hsum = fmaxf((h0 + h1) + h2, 0.f);
            const float4 wa = *(const float4*)&w2t[c][0];
            const float4 wb = *(const float4*)&w2t[c][4];
            const float  w8 = w2t[c][8];
            acc[0] = fmaf(wa.x, hsum, acc[0]);
            acc[1] = fmaf(wa.y, hsum, acc[1]);
            acc[2] = fmaf(wa.z, hsum, acc[2]);
            acc[3] = fmaf(wa.w, hsum, acc[3]);
            acc[4] = fmaf(wb.x, hsum, acc[4]);
            acc[5] = fmaf(wb.y, hsum, acc[5]);
            acc[6] = fmaf(wb.z, hsum, acc[6]);
            acc[7] = fmaf(wb.w, hsum, acc[7]);
            acc[8] = fmaf(w8,  hsum, acc[8]);
        }
        #pragma unroll
        for (int t = 0; t < TAPS; ++t) kernS[t][x] = acc[t];
    }
    __syncthreads();

    const int lane = tid & 63;
    const int wav  = tid >> 6;
    const int x0   = lane * 4;

    float4 kt[TAPS];
    #pragma unroll
    for (int t = 0; t < TAPS; ++t) kt[t] = *(const float4*)&kernS[t][x0];

    #pragma unroll 4
    for (int cc = 0; cc < 16; ++cc) {
        const int c = wav * 16 + cc;
        const float* hb = hin + (size_t)(b * C_ + c) * H_ * W_;

        float4 rowv[3];
        float  lft[3], rgt[3];
        #pragma unroll
        for (int r = 0; r < 3; ++r) {
            const int yy = y + r - 1;
            const bool vy = (unsigned)yy < (unsigned)H_;
            float4 m;
            if (vy) m = *(const float4*)(hb + (size_t)yy * W_ + x0);
            else    m = make_float4(0.f, 0.f, 0.f, 0.f);
            rowv[r] = m;
            float l  = __shfl_up(m.w, 1);
            float rr = __shfl_down(m.x, 1);
            if (lane == 0)  l  = 0.f;
            if (lane == 63) rr = 0.f;
            lft[r] = l; rgt[r] = rr;
        }

        float sim0 = 0.f, sim1 = 0.f, sim2 = 0.f, sim3 = 0.f;
        #pragma unroll
        for (int r = 0; r < 3; ++r) {
            const float w6_0 = lft[r];
            const float w6_1 = rowv[r].x;
            const float w6_2 = rowv[r].y;
            const float w6_3 = rowv[r].z;
            const float w6_4 = rowv[r].w;
            const float w6_5 = rgt[r];
            { const float4 k4 = kt[r*3+0];
              sim0 = fmaf(w6_0, k4.x, sim0); sim1 = fmaf(w6_1, k4.y, sim1);
              sim2 = fmaf(w6_2, k4.z, sim2); sim3 = fmaf(w6_3, k4.w, sim3); }
            { const float4 k4 = kt[r*3+1];
              sim0 = fmaf(w6_1, k4.x, sim0); sim1 = fmaf(w6_2, k4.y, sim1);
              sim2 = fmaf(w6_3, k4.z, sim2); sim3 = fmaf(w6_4, k4.w, sim3); }
            { const float4 k4 = kt[r*3+2];
              sim0 = fmaf(w6_2, k4.x, sim0); sim1 = fmaf(w6_3, k4.y, sim1);
              sim2 = fmaf(w6_4, k4.z, sim2); sim3 = fmaf(w6_5, k4.w, sim3); }
        }

        float4 o;
        o.x = rowv[1].x * __builtin_amdgcn_rcpf(1.f + __expf(-sim0));
        o.y = rowv[1].y * __builtin_amdgcn_rcpf(1.f + __expf(-sim1));
        o.z = rowv[1].z * __builtin_amdgcn_rcpf(1.f + __expf(-sim2));
        o.w = rowv[1].w * __builtin_amdgcn_rcpf(1.f + __expf(-sim3));
        *(float4*)(out + ((size_t)(b * C_ + c) * H_ + y) * W_ + x0) = o;
    }
}

extern "C" void kernel_launch(void* const* d_in, const int* in_sizes, int n_in,
                              void* d_out, int out_size, void* d_ws, size_t ws_size,
                              hipStream_t stream) {
    const float* lr  = (const float*)d_in[0];  // [8,3,256,256]
    const float* hin = (const float*)d_in[1];  // [8,64,256,256]
    const float* w1  = (const float*)d_in[2];  // [64,3,3,3]
    const float* b1  = (const float*)d_in[3];  // [64]
    const float* w2  = (const float*)d_in[4];  // [9,64,1,1]
    const float* b2  = (const float*)d_in[5];  // [9]
    float* out = (float*)d_out;                // [8,64,256,256]

    const size_t kern_bytes = (size_t)B_ * H_ * TAPS * W_ * sizeof(unsigned short);

    if (ws_size >= kern_bytes) {
        unsigned short* kws = (unsigned short*)d_ws;
        hipLaunchKernelGGL(hsa_kern, dim3(B_ * H_), dim3(256), 0, stream,
                           lr, w1, b1, w2, b2, kws);
        // 8 batches x 32 strips(8 rows) x 4 channel-groups = 1024 blocks
        hipLaunchKernelGGL(hsa_gate, dim3(1024), dim3(256), 0, stream,
                           hin, kws, out);
    } else {
        hipLaunchKernelGGL(hsa_fused, dim3(B_ * H_), dim3(256), 0, stream,
                           lr, hin, w1, b1, w2, b2, out);
    }
}

// Round 15
// 89.389 us; speedup vs baseline: 1.9895x; 1.0487x over previous
//
#include <hip/hip_runtime.h>
#include <hip/hip_bf16.h>
#include <math.h>

// Problem constants (from reference setup_inputs)
constexpr int B_  = 8;
constexpr int CIN = 3;
constexpr int C_  = 64;
constexpr int H_  = 256;
constexpr int W_  = 256;
constexpr int TAPS = 9;   // K*K, K=3
constexpr int KROW = TAPS * W_ / 2;   // u32 words per bf16 kern row (1152)

typedef float f32x4 __attribute__((ext_vector_type(4)));
typedef unsigned int u32x2 __attribute__((ext_vector_type(2)));

static __device__ __forceinline__ unsigned short f2bf(float f) {
    // RNE f32 -> bf16 (no NaN handling needed for this data)
    unsigned int u = __float_as_uint(f);
    unsigned int r = (u + 0x7fffu + ((u >> 16) & 1u)) >> 16;
    return (unsigned short)r;
}

// ============================================================================
// Kernel 1 (compute-bound, at the f32 VALU roofline ~14us): kern in BF16
// ============================================================================
__global__ __launch_bounds__(256, 4)
void hsa_kern(const float* __restrict__ lr,
              const float* __restrict__ w1,
              const float* __restrict__ b1,
              const float* __restrict__ w2,
              const float* __restrict__ b2,
              unsigned short* __restrict__ kws)
{
    __shared__ float w2t[C_][12];       // transposed 1x1 weights

    const int tid = threadIdx.x;
    const int blk = blockIdx.x;         // 0 .. B_*H_-1
    const int b = blk / H_;
    const int y = blk % H_;

    for (int i = tid; i < TAPS * C_; i += 256) {
        const int t = i / C_;
        const int c = i % C_;
        w2t[c][t] = w2[i];
    }
    __syncthreads();

    const int x = tid;                  // 0..255
    float win[CIN][3][3];
    #pragma unroll
    for (int ci = 0; ci < CIN; ++ci) {
        #pragma unroll
        for (int r = 0; r < 3; ++r) {
            const int yy = y + r - 1;
            const bool vy = (unsigned)yy < (unsigned)H_;
            const float* row = lr + ((size_t)(b * CIN + ci) * H_ + yy) * W_;
            win[ci][r][0] = (vy && x > 0)       ? row[x - 1] : 0.f;
            win[ci][r][1] = vy                   ? row[x]     : 0.f;
            win[ci][r][2] = (vy && x < W_ - 1)  ? row[x + 1] : 0.f;
        }
    }

    float acc[TAPS];
    #pragma unroll
    for (int t = 0; t < TAPS; ++t) acc[t] = b2[t];

    for (int c = 0; c < C_; ++c) {
        const float* wc = w1 + c * 27;
        float h0 = b1[c], h1 = 0.f, h2 = 0.f;
        #pragma unroll
        for (int r = 0; r < 3; ++r)
            #pragma unroll
            for (int j = 0; j < 3; ++j) {
                h0 = fmaf(wc[(0 * 3 + r) * 3 + j], win[0][r][j], h0);
                h1 = fmaf(wc[(1 * 3 + r) * 3 + j], win[1][r][j], h1);
                h2 = fmaf(wc[(2 * 3 + r) * 3 + j], win[2][r][j], h2);
            }
        const float hsum = fmaxf((h0 + h1) + h2, 0.f);   // ReLU

        const float4 wa = *(const float4*)&w2t[c][0];
        const float4 wb = *(const float4*)&w2t[c][4];
        const float  w8 = w2t[c][8];
        acc[0] = fmaf(wa.x, hsum, acc[0]);
        acc[1] = fmaf(wa.y, hsum, acc[1]);
        acc[2] = fmaf(wa.z, hsum, acc[2]);
        acc[3] = fmaf(wa.w, hsum, acc[3]);
        acc[4] = fmaf(wb.x, hsum, acc[4]);
        acc[5] = fmaf(wb.y, hsum, acc[5]);
        acc[6] = fmaf(wb.z, hsum, acc[6]);
        acc[7] = fmaf(wb.w, hsum, acc[7]);
        acc[8] = fmaf(w8,  hsum, acc[8]);
    }

    unsigned short* kr = kws + (size_t)(b * H_ + y) * (TAPS * W_);
    #pragma unroll
    for (int t = 0; t < TAPS; ++t) kr[t * W_ + x] = f2bf(acc[t]);
}

// ============================================================================
// Kernel 2 (gate): out = h * sigmoid(sum_taps shifted(h) * kern)
// R14 structure minus the two serializers (R15):
//  - NO LDS / NO barriers: kern taps read directly as bf16 dwordx2 from L2
//    (XCD-hot; 16x re-read = ~150 MB L2-level, far under the 34 TB/s L2
//    ceiling). With no barrier fences and a fully unrolled row loop, the
//    compiler is free to pipeline loads ACROSS row iterations — the per-iter
//    __syncthreads was both a 4-wave convoy stall (8x per block) and a
//    compiler fence (R10~R11 equivalence at f32; bf16 halves the direct cost).
//  - NON-TEMPORAL stores: out is never re-read; keeps L2 clean for h-halo
//    and kern re-reads.
// ============================================================================
__global__ __launch_bounds__(256, 4)
void hsa_gate(const float* __restrict__ hin,
              const unsigned short* __restrict__ kws,
              float* __restrict__ out)
{
    const int tid = threadIdx.x;
    const int bid = blockIdx.x;          // 0..1023
    // bijective XCD swizzle: 1024 = 8 XCDs x 128; each XCD owns one batch.
    const int nb  = (bid & 7) * 128 + (bid >> 3);
    const int b     = nb >> 7;           // 0..7
    const int strip = (nb >> 2) & 31;    // 0..31
    const int cg    = nb & 3;            // 0..3
    const int Y     = strip * 8;

    const int lane = tid & 63;
    const int wv   = tid >> 6;           // 0..3
    const int x0   = lane * 4;
    const int c0   = cg * 16 + wv * 4;   // this wave's 4 channels

    const size_t plane = (size_t)H_ * W_;
    const float* hb = hin + ((size_t)b * C_ + c0) * plane;
    float*       ob = out + ((size_t)b * C_ + c0) * plane;
    const unsigned int* kbase = (const unsigned int*)kws + (size_t)b * H_ * KROW;

    const float lmask = (lane > 0)  ? 1.f : 0.f;
    const float rmask = (lane < 63) ? 1.f : 0.f;

    f32x4 win[3][4];        // 3-row h window x 4 channels

    // ---- prologue: fill 3-row h window ----
    {
        const int ym = (Y > 0) ? (Y - 1) : 0;   // clamped; masked via kt
        #pragma unroll
        for (int i = 0; i < 4; ++i)
            win[0][i] = *(const f32x4*)(hb + i * plane + (size_t)ym      * W_ + x0);
        #pragma unroll
        for (int i = 0; i < 4; ++i)
            win[1][i] = *(const f32x4*)(hb + i * plane + (size_t)Y       * W_ + x0);
        #pragma unroll
        for (int i = 0; i < 4; ++i)
            win[2][i] = *(const f32x4*)(hb + i * plane + (size_t)(Y + 1) * W_ + x0);
    }

    #pragma unroll
    for (int yy = 0; yy < 8; ++yy) {
        const int yg = Y + yy;

        // kern taps: direct bf16 dwordx2 loads (L2-hot), expanded by bit-ops
        f32x4 kt[TAPS];
        {
            const unsigned int* kr = kbase + (size_t)yg * KROW + lane * 2;
            #pragma unroll
            for (int t = 0; t < TAPS; ++t) {
                const u32x2 w = *(const u32x2*)(kr + t * 128);
                kt[t].x = __uint_as_float(w.x << 16);
                kt[t].y = __uint_as_float(w.x & 0xffff0000u);
                kt[t].z = __uint_as_float(w.y << 16);
                kt[t].w = __uint_as_float(w.y & 0xffff0000u);
            }
        }

        // next h row (enters window at end of this iter; loads free to float)
        f32x4 nxt[4];
        if (yy < 7) {
            const int yn = (yg + 2 < H_) ? (yg + 2) : (H_ - 1);
            #pragma unroll
            for (int i = 0; i < 4; ++i)
                nxt[i] = *(const f32x4*)(hb + i * plane + (size_t)yn * W_ + x0);
        }

        // fold ALL boundary masks into kt
        const float m0 = (yg > 0)      ? 1.f : 0.f;
        const float m2 = (yg < H_ - 1) ? 1.f : 0.f;
        #pragma unroll
        for (int t = 0; t < 3; ++t) { kt[t] *= m0; kt[6 + t] *= m2; }
        kt[0].x *= lmask; kt[3].x *= lmask; kt[6].x *= lmask;
        kt[2].w *= rmask; kt[5].w *= rmask; kt[8].w *= rmask;

        // compute 4 channels (pure FMA + 2 shuffles per row-channel)
        float sim[4][4];
        #pragma unroll
        for (int i = 0; i < 4; ++i)
            #pragma unroll
            for (int j = 0; j < 4; ++j) sim[i][j] = 0.f;

        #pragma unroll
        for (int r = 0; r < 3; ++r) {
            const int sl = (yy + r) % 3;          // compile-time after unroll
            const f32x4 k0 = kt[r * 3 + 0];
            const f32x4 k1 = kt[r * 3 + 1];
            const f32x4 k2 = kt[r * 3 + 2];
            #pragma unroll
            for (int i = 0; i < 4; ++i) {
                const f32x4 cv = win[sl][i];
                const float l  = __shfl_up(cv.w, 1);    // x0-1 (lane0 masked via kt)
                const float rr = __shfl_down(cv.x, 1);  // x0+4 (lane63 masked via kt)
                sim[i][0] = fmaf(l,    k0.x, fmaf(cv.x, k1.x, fmaf(cv.y, k2.x, sim[i][0])));
                sim[i][1] = fmaf(cv.x, k0.y, fmaf(cv.y, k1.y, fmaf(cv.z, k2.y, sim[i][1])));
                sim[i][2] = fmaf(cv.y, k0.z, fmaf(cv.z, k1.z, fmaf(cv.w, k2.z, sim[i][2])));
                sim[i][3] = fmaf(cv.z, k0.w, fmaf(cv.w, k1.w, fmaf(rr,   k2.w, sim[i][3])));
            }
        }

        // gate + non-temporal store (out never re-read; keep L2 for h/kern)
        #pragma unroll
        for (int i = 0; i < 4; ++i) {
            const f32x4 ctr = win[(yy + 1) % 3][i];
            f32x4 o;
            o.x = ctr.x * __builtin_amdgcn_rcpf(1.f + __expf(-sim[i][0]));
            o.y = ctr.y * __builtin_amdgcn_rcpf(1.f + __expf(-sim[i][1]));
            o.z = ctr.z * __builtin_amdgcn_rcpf(1.f + __expf(-sim[i][2]));
            o.w = ctr.w * __builtin_amdgcn_rcpf(1.f + __expf(-sim[i][3]));
            __builtin_nontemporal_store(o, (f32x4*)(ob + i * plane + (size_t)yg * W_ + x0));
        }

        // rotate h window (SSA renaming after full unroll)
        if (yy < 7) {
            #pragma unroll
            for (int i = 0; i < 4; ++i) win[yy % 3][i] = nxt[i];
        }
    }
}

// ============================================================================
// Fallback: single fused kernel (used only if ws_size is too small)
// ============================================================================
__global__ __launch_bounds__(256, 4)
void hsa_fused(const float* __restrict__ lr,
               const float* __restrict__ hin,
               const float* __restrict__ w1,
               const float* __restrict__ b1,
               const float* __restrict__ w2,
               const float* __restrict__ b2,
               float* __restrict__ out)
{
    __shared__ float kernS[TAPS][W_];
    __shared__ float w2t[C_][12];

    const int tid = threadIdx.x;
    const int blk = blockIdx.x;
    const int b = blk / H_;
    const int y = blk % H_;

    for (int i = tid; i < TAPS * C_; i += 256) {
        const int t = i / C_;
        const int c = i % C_;
        w2t[c][t] = w2[i];
    }
    __syncthreads();

    {
        const int x = tid;
        float win[CIN][3][3];
        #pragma unroll
        for (int ci = 0; ci < CIN; ++ci)
            #pragma unroll
            for (int r = 0; r < 3; ++r) {
                const int yy = y + r - 1;
                const bool vy = (unsigned)yy < (unsigned)H_;
                const float* row = lr + ((size_t)(b * CIN + ci) * H_ + yy) * W_;
                win[ci][r][0] = (vy && x > 0)      ? row[x - 1] : 0.f;
                win[ci][r][1] = vy                  ? row[x]     : 0.f;
                win[ci][r][2] = (vy && x < W_ - 1) ? row[x + 1] : 0.f;
            }

        float acc[TAPS];
        #pragma unroll
        for (int t = 0; t < TAPS; ++t) acc[t] = b2[t];

        for (int c = 0; c < C_; ++c) {
            const float* wc = w1 + c * 27;
            float h0 = b1[c], h1 = 0.f, h2 = 0.f;
            #pragma unroll
            for (int r = 0; r < 3; ++r)
                #pragma unroll
                for (int j = 0; j < 3; ++j) {
                    h0 = fmaf(wc[(0 * 3 + r) * 3 + j], win[0][r][j], h0);
                    h1 = fmaf(wc[(1 * 3 + r) * 3 + j], win[1][r][j], h1);
                    h2 = fmaf(wc[(2 * 3 + r) * 3 + j], win[2][r][j], h2);
                }
            const float hsum = fmaxf((h0 + h1) + h2, 0.f);
            const float4 wa = *(const float4*)&w2t[c][0];
            const float4 wb = *(const float4*)&w2t[c][4];
            const float  w8 = w2t[c][8];
            acc[0] = fmaf(wa.x, hsum, acc[0]);
            acc[1] = fmaf(wa.y, hsum, acc[1]);
            acc[2] = fmaf(wa.z, hsum, acc[2]);
            acc[3] = fmaf(wa.w, hsum, acc[3]);
            acc[4] = fmaf(wb.x, hsum, acc[4]);
            acc[5] = fmaf(wb.y, hsum, acc[5]);
            acc[6] = fmaf(wb.z, hsum, acc[6]);
            acc[7] = fmaf(wb.w, hsum, acc[7]);
            acc[8] = fmaf(w8,  hsum, acc[8]);
        }
        #pragma unroll
        for (int t = 0; t < TAPS; ++t) kernS[t][x] = acc[t];
    }
    __syncthreads();

    const int lane = tid & 63;
    const int wav  = tid >> 6;
    const int x0   = lane * 4;

    float4 kt[TAPS];
    #pragma unroll
    for (int t = 0; t < TAPS; ++t) kt[t] = *(const float4*)&kernS[t][x0];

    #pragma unroll 4
    for (int cc = 0; cc < 16; ++cc) {
        const int c = wav * 16 + cc;
        const float* hb = hin + (size_t)(b * C_ + c) * H_ * W_;

        float4 rowv[3];
        float  lft[3], rgt[3];
        #pragma unroll
        for (int r = 0; r < 3; ++r) {
            const int yy = y + r - 1;
            const bool vy = (unsigned)yy < (unsigned)H_;
            float4 m;
            if (vy) m = *(const float4*)(hb + (size_t)yy * W_ + x0);
            else    m = make_float4(0.f, 0.f, 0.f, 0.f);
            rowv[r] = m;
            float l  = __shfl_up(m.w, 1);
            float rr = __shfl_down(m.x, 1);
            if (lane == 0)  l  = 0.f;
            if (lane == 63) rr = 0.f;
            lft[r] = l; rgt[r] = rr;
        }

        float sim0 = 0.f, sim1 = 0.f, sim2 = 0.f, sim3 = 0.f;
        #pragma unroll
        for (int r = 0; r < 3; ++r) {
            const float w6_0 = lft[r];
            const float w6_1 = rowv[r].x;
            const float w6_2 = rowv[r].y;
            const float w6_3 = rowv[r].z;
            const float w6_4 = rowv[r].w;
            const float w6_5 = rgt[r];
            { const float4 k4 = kt[r*3+0];
              sim0 = fmaf(w6_0, k4.x, sim0); sim1 = fmaf(w6_1, k4.y, sim1);
              sim2 = fmaf(w6_2, k4.z, sim2); sim3 = fmaf(w6_3, k4.w, sim3); }
            { const float4 k4 = kt[r*3+1];
              sim0 = fmaf(w6_1, k4.x, sim0); sim1 = fmaf(w6_2, k4.y, sim1);
              sim2 = fmaf(w6_3, k4.z, sim2); sim3 = fmaf(w6_4, k4.w, sim3); }
            { const float4 k4 = kt[r*3+2];
              sim0 = fmaf(w6_2, k4.x, sim0); sim1 = fmaf(w6_3, k4.y, sim1);
              sim2 = fmaf(w6_4, k4.z, sim2); sim3 = fmaf(w6_5, k4.w, sim3); }
        }

        float4 o;
        o.x = rowv[1].x * __builtin_amdgcn_rcpf(1.f + __expf(-sim0));
        o.y = rowv[1].y * __builtin_amdgcn_rcpf(1.f + __expf(-sim1));
        o.z = rowv[1].z * __builtin_amdgcn_rcpf(1.f + __expf(-sim2));
        o.w = rowv[1].w * __builtin_amdgcn_rcpf(1.f + __expf(-sim3));
        *(float4*)(out + ((size_t)(b * C_ + c) * H_ + y) * W_ + x0) = o;
    }
}

extern "C" void kernel_launch(void* const* d_in, const int* in_sizes, int n_in,
                              void* d_out, int out_size, void* d_ws, size_t ws_size,
                              hipStream_t stream) {
    const float* lr  = (const float*)d_in[0];  // [8,3,256,256]
    const float* hin = (const float*)d_in[1];  // [8,64,256,256]
    const float* w1  = (const float*)d_in[2];  // [64,3,3,3]
    const float* b1  = (const float*)d_in[3];  // [64]
    const float* w2  = (const float*)d_in[4];  // [9,64,1,1]
    const float* b2  = (const float*)d_in[5];  // [9]
    float* out = (float*)d_out;                // [8,64,256,256]

    const size_t kern_bytes = (size_t)B_ * H_ * TAPS * W_ * sizeof(unsigned short);

    if (ws_size >= kern_bytes) {
        unsigned short* kws = (unsigned short*)d_ws;
        hipLaunchKernelGGL(hsa_kern, dim3(B_ * H_), dim3(256), 0, stream,
                           lr, w1, b1, w2, b2, kws);
        // 8 batches x 32 strips(8 rows) x 4 channel-groups = 1024 blocks
        hipLaunchKernelGGL(hsa_gate, dim3(1024), dim3(256), 0, stream,
                           hin, kws, out);
    } else {
        hipLaunchKernelGGL(hsa_fused, dim3(B_ * H_), dim3(256), 0, stream,
                           lr, hin, w1, b1, w2, b2, out);
    }
}

// Round 16
// 82.831 us; speedup vs baseline: 2.1470x; 1.0792x over previous
//
#include <hip/hip_runtime.h>
#include <hip/hip_bf16.h>
#include <math.h>

// Problem constants (from reference setup_inputs)
constexpr int B_  = 8;
constexpr int CIN = 3;
constexpr int C_  = 64;
constexpr int H_  = 256;
constexpr int W_  = 256;
constexpr int TAPS = 9;   // K*K, K=3
constexpr int KROW = TAPS * W_ / 2;   // u32 words per bf16 kern row (1152)

typedef float f32x4 __attribute__((ext_vector_type(4)));
typedef unsigned int u32x2 __attribute__((ext_vector_type(2)));
typedef unsigned int u32x4 __attribute__((ext_vector_type(4)));

static __device__ __forceinline__ unsigned short f2bf(float f) {
    // RNE f32 -> bf16 (no NaN handling needed for this data)
    unsigned int u = __float_as_uint(f);
    unsigned int r = (u + 0x7fffu + ((u >> 16) & 1u)) >> 16;
    return (unsigned short)r;
}

// ============================================================================
// Kernel 1 (compute-bound): kern = conv1x1(relu(conv3x3(lr))), BF16 out
// ============================================================================
__global__ __launch_bounds__(256, 4)
void hsa_kern(const float* __restrict__ lr,
              const float* __restrict__ w1,
              const float* __restrict__ b1,
              const float* __restrict__ w2,
              const float* __restrict__ b2,
              unsigned short* __restrict__ kws)
{
    __shared__ float w2t[C_][12];       // transposed 1x1 weights

    const int tid = threadIdx.x;
    const int blk = blockIdx.x;         // 0 .. B_*H_-1
    const int b = blk / H_;
    const int y = blk % H_;

    for (int i = tid; i < TAPS * C_; i += 256) {
        const int t = i / C_;
        const int c = i % C_;
        w2t[c][t] = w2[i];
    }
    __syncthreads();

    const int x = tid;                  // 0..255
    float win[CIN][3][3];
    #pragma unroll
    for (int ci = 0; ci < CIN; ++ci) {
        #pragma unroll
        for (int r = 0; r < 3; ++r) {
            const int yy = y + r - 1;
            const bool vy = (unsigned)yy < (unsigned)H_;
            const float* row = lr + ((size_t)(b * CIN + ci) * H_ + yy) * W_;
            win[ci][r][0] = (vy && x > 0)       ? row[x - 1] : 0.f;
            win[ci][r][1] = vy                   ? row[x]     : 0.f;
            win[ci][r][2] = (vy && x < W_ - 1)  ? row[x + 1] : 0.f;
        }
    }

    float acc[TAPS];
    #pragma unroll
    for (int t = 0; t < TAPS; ++t) acc[t] = b2[t];

    for (int c = 0; c < C_; ++c) {
        const float* wc = w1 + c * 27;
        float h0 = b1[c], h1 = 0.f, h2 = 0.f;
        #pragma unroll
        for (int r = 0; r < 3; ++r)
            #pragma unroll
            for (int j = 0; j < 3; ++j) {
                h0 = fmaf(wc[(0 * 3 + r) * 3 + j], win[0][r][j], h0);
                h1 = fmaf(wc[(1 * 3 + r) * 3 + j], win[1][r][j], h1);
                h2 = fmaf(wc[(2 * 3 + r) * 3 + j], win[2][r][j], h2);
            }
        const float hsum = fmaxf((h0 + h1) + h2, 0.f);   // ReLU

        const float4 wa = *(const float4*)&w2t[c][0];
        const float4 wb = *(const float4*)&w2t[c][4];
        const float  w8 = w2t[c][8];
        acc[0] = fmaf(wa.x, hsum, acc[0]);
        acc[1] = fmaf(wa.y, hsum, acc[1]);
        acc[2] = fmaf(wa.z, hsum, acc[2]);
        acc[3] = fmaf(wa.w, hsum, acc[3]);
        acc[4] = fmaf(wb.x, hsum, acc[4]);
        acc[5] = fmaf(wb.y, hsum, acc[5]);
        acc[6] = fmaf(wb.z, hsum, acc[6]);
        acc[7] = fmaf(wb.w, hsum, acc[7]);
        acc[8] = fmaf(w8,  hsum, acc[8]);
    }

    unsigned short* kr = kws + (size_t)(b * H_ + y) * (TAPS * W_);
    #pragma unroll
    for (int t = 0; t < TAPS; ++t) kr[t * W_ + x] = f2bf(acc[t]);
}

// ============================================================================
// Kernel 2 (gate): out = h * sigmoid(sum_taps shifted(h) * kern)
// COPY-SHAPED STREAMING (R16): per-CU BW was pinned at ~12.5 GB/s (half of
// copy's ~25) across R11/R13/R15 regardless of occupancy — suspect VMEM
// request-rate / DRAM stream thrash: 17 VMEM/iter at 740B avg, ~144 address
// streams per CU. Fix:
//  - 1 channel per WAVE (block = b x 8-row strip x 4-channel group; 4096 blk)
//  - stage the strip's ENTIRE 8 kern rows in LDS once (36 KB, one barrier,
//    u32x4 coop loads) -> kern leaves the VMEM path (ds_read_b64 in loop)
//  - steady state per wave per iter: 1 h load + 1 NT store = 2 VMEM instrs,
//    2 sequential streams, 1KB/instr — copy parity.
// ============================================================================
__global__ __launch_bounds__(256, 4)
void hsa_gate(const float* __restrict__ hin,
              const unsigned short* __restrict__ kws,
              float* __restrict__ out)
{
    __shared__ unsigned int ksh[8][KROW];   // 36 KB: 8 bf16 kern rows

    const int tid = threadIdx.x;
    const int bid = blockIdx.x;          // 0..4095
    // bijective XCD swizzle: 4096 = 8 XCDs x 512; each XCD owns one batch.
    const int nb  = (bid & 7) * 512 + (bid >> 3);
    const int b     = nb >> 9;           // 0..7
    const int strip = (nb >> 4) & 31;    // 0..31
    const int cg    = nb & 15;           // 0..15 (consecutive nb share kern rows)
    const int Y     = strip * 8;

    const int lane = tid & 63;
    const int wv   = tid >> 6;           // 0..3
    const int x0   = lane * 4;
    const int c0   = cg * 4 + wv;        // this wave's single channel

    const size_t plane = (size_t)H_ * W_;
    const float* hb = hin + ((size_t)b * C_ + c0) * plane;
    float*       ob = out + ((size_t)b * C_ + c0) * plane;
    const unsigned int* kbase = (const unsigned int*)kws + (size_t)b * H_ * KROW;

    const float lmask = (lane > 0)  ? 1.f : 0.f;
    const float rmask = (lane < 63) ? 1.f : 0.f;

    // ---- stage 8 kern rows cooperatively: 9216 u32 = 9 x u32x4 per thread --
    {
        const unsigned int* kr = kbase + (size_t)Y * KROW;  // rows contiguous
        unsigned int* ksf = &ksh[0][0];
        #pragma unroll
        for (int i = 0; i < 9; ++i) {
            const int idx = (tid + i * 256) * 4;
            *(u32x4*)(ksf + idx) = *(const u32x4*)(kr + idx);
        }
    }

    // ---- prologue: 3-row h window for this wave's channel ----
    f32x4 wA, wB, wC;
    {
        const int ym = (Y > 0) ? (Y - 1) : 0;   // clamped; masked via kt
        wA = *(const f32x4*)(hb + (size_t)ym      * W_ + x0);
        wB = *(const f32x4*)(hb + (size_t)Y       * W_ + x0);
        wC = *(const f32x4*)(hb + (size_t)(Y + 1) * W_ + x0);
    }
    __syncthreads();   // kern staging visible; only barrier in the kernel

    #pragma unroll
    for (int yy = 0; yy < 8; ++yy) {
        const int yg = Y + yy;

        // next h row (the wave's ONLY VMEM load this iter; sequential stream)
        f32x4 nxt;
        if (yy < 7) {
            const int yn = (yg + 2 < H_) ? (yg + 2) : (H_ - 1);
            nxt = *(const f32x4*)(hb + (size_t)yn * W_ + x0);
        }

        // kern taps from LDS (bf16 pairs -> f32 bit-ops, exact)
        f32x4 kt[TAPS];
        #pragma unroll
        for (int t = 0; t < TAPS; ++t) {
            const u32x2 w = *(const u32x2*)&ksh[yy][t * 128 + lane * 2];
            kt[t].x = __uint_as_float(w.x << 16);
            kt[t].y = __uint_as_float(w.x & 0xffff0000u);
            kt[t].z = __uint_as_float(w.y << 16);
            kt[t].w = __uint_as_float(w.y & 0xffff0000u);
        }

        // fold ALL boundary masks into kt
        const float m0 = (yg > 0)      ? 1.f : 0.f;
        const float m2 = (yg < H_ - 1) ? 1.f : 0.f;
        #pragma unroll
        for (int t = 0; t < 3; ++t) { kt[t] *= m0; kt[6 + t] *= m2; }
        kt[0].x *= lmask; kt[3].x *= lmask; kt[6].x *= lmask;
        kt[2].w *= rmask; kt[5].w *= rmask; kt[8].w *= rmask;

        // compute this channel (pure FMA + 2 shuffles per window row)
        float sim0 = 0.f, sim1 = 0.f, sim2 = 0.f, sim3 = 0.f;
        #pragma unroll
        for (int r = 0; r < 3; ++r) {
            const f32x4 cv = (r == 0) ? wA : (r == 1) ? wB : wC;
            const float l  = __shfl_up(cv.w, 1);    // x0-1 (lane0 masked via kt)
            const float rr = __shfl_down(cv.x, 1);  // x0+4 (lane63 masked via kt)
            const f32x4 k0 = kt[r * 3 + 0];
            const f32x4 k1 = kt[r * 3 + 1];
            const f32x4 k2 = kt[r * 3 + 2];
            sim0 = fmaf(l,    k0.x, fmaf(cv.x, k1.x, fmaf(cv.y, k2.x, sim0)));
            sim1 = fmaf(cv.x, k0.y, fmaf(cv.y, k1.y, fmaf(cv.z, k2.y, sim1)));
            sim2 = fmaf(cv.y, k0.z, fmaf(cv.z, k1.z, fmaf(cv.w, k2.z, sim2)));
            sim3 = fmaf(cv.z, k0.w, fmaf(cv.w, k1.w, fmaf(rr,   k2.w, sim3)));
        }

        // gate + non-temporal store (sequential write stream)
        f32x4 o;
        o.x = wB.x * __builtin_amdgcn_rcpf(1.f + __expf(-sim0));
        o.y = wB.y * __builtin_amdgcn_rcpf(1.f + __expf(-sim1));
        o.z = wB.z * __builtin_amdgcn_rcpf(1.f + __expf(-sim2));
        o.w = wB.w * __builtin_amdgcn_rcpf(1.f + __expf(-sim3));
        __builtin_nontemporal_store(o, (f32x4*)(ob + (size_t)yg * W_ + x0));

        // slide window (SSA renames after full unroll)
        if (yy < 7) { wA = wB; wB = wC; wC = nxt; }
    }
}

// ============================================================================
// Fallback: single fused kernel (used only if ws_size is too small)
// ============================================================================
__global__ __launch_bounds__(256, 4)
void hsa_fused(const float* __restrict__ lr,
               const float* __restrict__ hin,
               const float* __restrict__ w1,
               const float* __restrict__ b1,
               const float* __restrict__ w2,
               const float* __restrict__ b2,
               float* __restrict__ out)
{
    __shared__ float kernS[TAPS][W_];
    __shared__ float w2t[C_][12];

    const int tid = threadIdx.x;
    const int blk = blockIdx.x;
    const int b = blk / H_;
    const int y = blk % H_;

    for (int i = tid; i < TAPS * C_; i += 256) {
        const int t = i / C_;
        const int c = i % C_;
        w2t[c][t] = w2[i];
    }
    __syncthreads();

    {
        const int x = tid;
        float win[CIN][3][3];
        #pragma unroll
        for (int ci = 0; ci < CIN; ++ci)
            #pragma unroll
            for (int r = 0; r < 3; ++r) {
                const int yy = y + r - 1;
                const bool vy = (unsigned)yy < (unsigned)H_;
                const float* row = lr + ((size_t)(b * CIN + ci) * H_ + yy) * W_;
                win[ci][r][0] = (vy && x > 0)      ? row[x - 1] : 0.f;
                win[ci][r][1] = vy                  ? row[x]     : 0.f;
                win[ci][r][2] = (vy && x < W_ - 1) ? row[x + 1] : 0.f;
            }

        float acc[TAPS];
        #pragma unroll
        for (int t = 0; t < TAPS; ++t) acc[t] = b2[t];

        for (int c = 0; c < C_; ++c) {
            const float* wc = w1 + c * 27;
            float h0 = b1[c], h1 = 0.f, h2 = 0.f;
            #pragma unroll
            for (int r = 0; r < 3; ++r)
                #pragma unroll
                for (int j = 0; j < 3; ++j) {
                    h0 = fmaf(wc[(0 * 3 + r) * 3 + j], win[0][r][j], h0);
                    h1 = fmaf(wc[(1 * 3 + r) * 3 + j], win[1][r][j], h1);
                    h2 = fmaf(wc[(2 * 3 + r) * 3 + j], win[2][r][j], h2);
                }
            const float hsum = fmaxf((h0 + h1) + h2, 0.f);
            const float4 wa = *(const float4*)&w2t[c][0];
            const float4 wb = *(const float4*)&w2t[c][4];
            const float  w8 = w2t[c][8];
            acc[0] = fmaf(wa.x, hsum, acc[0]);
            acc[1] = fmaf(wa.y, hsum, acc[1]);
            acc[2] = fmaf(wa.z, hsum, acc[2]);
            acc[3] = fmaf(wa.w, hsum, acc[3]);
            acc[4] = fmaf(wb.x, hsum, acc[4]);
            acc[5] = fmaf(wb.y, hsum, acc[5]);
            acc[6] = fmaf(wb.z, hsum, acc[6]);
            acc[7] = fmaf(wb.w, hsum, acc[7]);
            acc[8] = fmaf(w8,  hsum, acc[8]);
        }
        #pragma unroll
        for (int t = 0; t < TAPS; ++t) kernS[t][x] = acc[t];
    }
    __syncthreads();

    const int lane = tid & 63;
    const int wav  = tid >> 6;
    const int x0   = lane * 4;

    float4 kt[TAPS];
    #pragma unroll
    for (int t = 0; t < TAPS; ++t) kt[t] = *(const float4*)&kernS[t][x0];

    #pragma unroll 4
    for (int cc = 0; cc < 16; ++cc) {
        const int c = wav * 16 + cc;
        const float* hb = hin + (size_t)(b * C_ + c) * H_ * W_;

        float4 rowv[3];
        float  lft[3], rgt[3];
        #pragma unroll
        for (int r = 0; r < 3; ++r) {
            const int yy = y + r - 1;
            const bool vy = (unsigned)yy < (unsigned)H_;
            float4 m;
            if (vy) m = *(const float4*)(hb + (size_t)yy * W_ + x0);
            else    m = make_float4(0.f, 0.f, 0.f, 0.f);
            rowv[r] = m;
            float l  = __shfl_up(m.w, 1);
            float rr = __shfl_down(m.x, 1);
            if (lane == 0)  l  = 0.f;
            if (lane == 63) rr = 0.f;
            lft[r] = l; rgt[r] = rr;
        }

        float sim0 = 0.f, sim1 = 0.f, sim2 = 0.f, sim3 = 0.f;
        #pragma unroll
        for (int r = 0; r < 3; ++r) {
            const float w6_0 = lft[r];
            const float w6_1 = rowv[r].x;
            const float w6_2 = rowv[r].y;
            const float w6_3 = rowv[r].z;
            const float w6_4 = rowv[r].w;
            const float w6_5 = rgt[r];
            { const float4 k4 = kt[r*3+0];
              sim0 = fmaf(w6_0, k4.x, sim0); sim1 = fmaf(w6_1, k4.y, sim1);
              sim2 = fmaf(w6_2, k4.z, sim2); sim3 = fmaf(w6_3, k4.w, sim3); }
            { const float4 k4 = kt[r*3+1];
              sim0 = fmaf(w6_1, k4.x, sim0); sim1 = fmaf(w6_2, k4.y, sim1);
              sim2 = fmaf(w6_3, k4.z, sim2); sim3 = fmaf(w6_4, k4.w, sim3); }
            { const float4 k4 = kt[r*3+2];
              sim0 = fmaf(w6_2, k4.x, sim0); sim1 = fmaf(w6_3, k4.y, sim1);
              sim2 = fmaf(w6_4, k4.z, sim2); sim3 = fmaf(w6_5, k4.w, sim3); }
        }

        float4 o;
        o.x = rowv[1].x * __builtin_amdgcn_rcpf(1.f + __expf(-sim0));
        o.y = rowv[1].y * __builtin_amdgcn_rcpf(1.f + __expf(-sim1));
        o.z = rowv[1].z * __builtin_amdgcn_rcpf(1.f + __expf(-sim2));
        o.w = rowv[1].w * __builtin_amdgcn_rcpf(1.f + __expf(-sim3));
        *(float4*)(out + ((size_t)(b * C_ + c) * H_ + y) * W_ + x0) = o;
    }
}

extern "C" void kernel_launch(void* const* d_in, const int* in_sizes, int n_in,
                              void* d_out, int out_size, void* d_ws, size_t ws_size,
                              hipStream_t stream) {
    const float* lr  = (const float*)d_in[0];  // [8,3,256,256]
    const float* hin = (const float*)d_in[1];  // [8,64,256,256]
    const float* w1  = (const float*)d_in[2];  // [64,3,3,3]
    const float* b1  = (const float*)d_in[3];  // [64]
    const float* w2  = (const float*)d_in[4];  // [9,64,1,1]
    const float* b2  = (const float*)d_in[5];  // [9]
    float* out = (float*)d_out;                // [8,64,256,256]

    const size_t kern_bytes = (size_t)B_ * H_ * TAPS * W_ * sizeof(unsigned short);

    if (ws_size >= kern_bytes) {
        unsigned short* kws = (unsigned short*)d_ws;
        hipLaunchKernelGGL(hsa_kern, dim3(B_ * H_), dim3(256), 0, stream,
                           lr, w1, b1, w2, b2, kws);
        // 8 batches x 32 strips(8 rows) x 16 channel-groups(4ch) = 4096 blocks
        hipLaunchKernelGGL(hsa_gate, dim3(4096), dim3(256), 0, stream,
                           hin, kws, out);
    } else {
        hipLaunchKernelGGL(hsa_fused, dim3(B_ * H_), dim3(256), 0, stream,
                           lr, hin, w1, b1, w2, b2, out);
    }
}